// Round 6
// baseline (132.394 us; speedup 1.0000x reference)
//
#include <hip/hip_runtime.h>
#include <hip/hip_bf16.h>

// Problem constants
#define Bk 8
#define Nk 10000
#define Ek 160000
#define Hk 128
#define Zk 64
#define CAPk 64     // bucket-CSR capacity; deg ~ Poisson(16), P(deg>=64) ~ 0
#define NTILES 313  // ceil(10000/32)

typedef float f32x4 __attribute__((ext_vector_type(4)));
typedef short s16x8 __attribute__((ext_vector_type(8)));

// init: pack WBT (128x256 bf16: [W2l | W2r] rows), zero cur + pooled
__global__ __launch_bounds__(256) void k0_init(const float* __restrict__ W2l, const float* __restrict__ W2r,
                                               __hip_bfloat16* __restrict__ wbt, int* __restrict__ cur,
                                               float* __restrict__ pooled){
  int t = blockIdx.x*256 + threadIdx.x;
  if (t < 128*256){
    int o = t >> 8, k = t & 255;
    float v = (k < 128) ? W2l[o*128+k] : W2r[o*128+(k-128)];
    wbt[t] = __float2bfloat16(v);
  }
  if (t < Nk) cur[t] = 0;
  if (t < Bk*Hk) pooled[t] = 0.f;
}

// bucket-CSR fill: csrsrc[d*CAP + p] = src, cur[d] = degree
__global__ void k3_fill(const int* __restrict__ ei, int* __restrict__ cur, int* __restrict__ csrsrc){
  int e = blockIdx.x*blockDim.x + threadIdx.x;
  if (e < Ek){
    int s = ei[e], d = ei[Ek+e];
    int p = atomicAdd(&cur[d], 1);
    if (p < CAPk) csrsrc[d*CAPk + p] = s;
  }
}

// agg1[b,i] = mean over incoming edges of x[b,src]
__global__ void k4_agg1(const float* __restrict__ x, const int* __restrict__ cur,
                        const int* __restrict__ csrsrc, float* __restrict__ agg1){
  int i = blockIdx.x*blockDim.x + threadIdx.x;
  int b = blockIdx.y;
  if (i >= Nk) return;
  int degc = cur[i];
  int deg = min(degc, CAPk);
  const float* xb = x + b*Nk;
  const int* col = csrsrc + i*CAPk;
  float sum=0.f;
  for (int k=0;k<deg;k++) sum += xb[col[k]];
  agg1[b*Nk+i] = sum / fmaxf((float)degc, 1.f);
}

// H1[b][i][h] = relu(agg1*w1l + x*w1r + b1), bf16. Wave per node row (64 lanes
// = 64 h-pairs), coalesced 256 B dword stores.
__global__ __launch_bounds__(256) void kA_h1(const float* __restrict__ x, const float* __restrict__ agg1,
                        const float* __restrict__ W1l, const float* __restrict__ b1,
                        const float* __restrict__ W1r, __hip_bfloat16* __restrict__ h1){
  int b = blockIdx.y;
  int i = blockIdx.x*4 + (threadIdx.x>>6);
  int hp = threadIdx.x & 63;
  if (i >= Nk) return;
  float a = agg1[b*Nk+i], xx = x[b*Nk+i];
  float2 wl = *(const float2*)(W1l + 2*hp);
  float2 wr = *(const float2*)(W1r + 2*hp);
  float2 bb = *(const float2*)(b1 + 2*hp);
  float v0 = fmaxf(fmaf(a, wl.x, fmaf(xx, wr.x, bb.x)), 0.f);
  float v1 = fmaxf(fmaf(a, wl.y, fmaf(xx, wr.y, bb.y)), 0.f);
  __hip_bfloat162 p; p.x = __float2bfloat16(v0); p.y = __float2bfloat16(v1);
  *(unsigned*)((void*)(h1 + ((size_t)b*Nk + i)*128 + 2*hp)) = *(unsigned*)&p;
}

__device__ inline void mfma_bf16(f32x4& d, s16x8 a, s16x8 b){
  asm("v_mfma_f32_16x16x32_bf16 %0, %1, %2, %0" : "+v"(d) : "v"(a), "v"(b));
}

// Fused: agg2 gather (neighbor-mean of H1 rows) -> LDS A-tile [agg2|h1] 32x256
// -> MFMA vs wbt -> relu+bias -> column-sum -> atomic pooled.
// grid dim3(8, NTILES): batch = blockIdx.x == XCD (linear id % 8) so each
// XCD's 2.56 MB H1 batch-slice stays L2-resident.
__global__ __launch_bounds__(256) void kB_fused(const __hip_bfloat16* __restrict__ h1,
                        const int* __restrict__ cur, const int* __restrict__ csrsrc,
                        const __hip_bfloat16* __restrict__ wbt, const float* __restrict__ b2,
                        float* __restrict__ pooled){
  __shared__ char At[32*512];   // 32 rows x 256 bf16, XOR-swizzled
  int b = blockIdx.x, tile = blockIdx.y;
  int wid = threadIdx.x >> 6, lane = threadIdx.x & 63;
  const __hip_bfloat16* h1b = h1 + (size_t)b*Nk*128;

  // phase 1: each wave aggregates 8 rows; lane = h-pair
  for (int c=0;c<8;c++){
    int r = wid*8 + c;
    int i = tile*32 + r;
    float ax = 0.f, ay = 0.f;
    unsigned sv = 0u;
    if (i < Nk){
      int degc = cur[i];
      int deg = min(degc, CAPk);
      const int* col = csrsrc + (size_t)i*CAPk;
      #pragma unroll 4
      for (int k=0;k<deg;k++){
        int j = col[k];   // wave-uniform -> s_load
        unsigned v = *(const unsigned*)((const void*)(h1b + (size_t)j*128 + 2*lane));
        ax += __uint_as_float(v << 16);
        ay += __uint_as_float(v & 0xffff0000u);
      }
      float inv = 1.f/fmaxf((float)degc, 1.f);
      ax *= inv; ay *= inv;
      sv = *(const unsigned*)((const void*)(h1b + (size_t)i*128 + 2*lane));
    }
    __hip_bfloat162 p; p.x = __float2bfloat16(ax); p.y = __float2bfloat16(ay);
    unsigned swz = (unsigned)((r & 7) << 4);
    *(unsigned*)(At + r*512 + ((4u*lane) ^ swz))        = *(unsigned*)&p;
    *(unsigned*)(At + r*512 + ((256u + 4u*lane) ^ swz)) = sv;
  }
  __syncthreads();

  // phase 2: GEMM 32x256 @ 256x128; wave w -> cols 32w..32w+31
  int lr = lane & 15, lk = lane >> 4;
  f32x4 acc[2][2];
  #pragma unroll
  for (int mf=0; mf<2; ++mf)
    #pragma unroll
    for (int q=0; q<2; ++q) acc[mf][q] = (f32x4){0.f,0.f,0.f,0.f};

  unsigned rsw = (unsigned)((lr & 7) << 4);
  #pragma unroll
  for (int kk=0; kk<8; ++kk){
    unsigned cb = kk*64 + lk*16;
    s16x8 a0 = *(const s16x8*)(At + lr*512      + (cb ^ rsw));
    s16x8 a1 = *(const s16x8*)(At + (16+lr)*512 + (cb ^ rsw));
    #pragma unroll
    for (int q=0; q<2; ++q){
      int nf = wid*2 + q;
      s16x8 bfr = *(const s16x8*)(const void*)(wbt + (nf*16+lr)*256 + kk*32 + lk*8);
      mfma_bf16(acc[0][q], a0, bfr);
      mfma_bf16(acc[1][q], a1, bfr);
    }
  }

  // epilogue: relu(acc + b2), mask pad rows, column-reduce, atomic into pooled
  #pragma unroll
  for (int q=0; q<2; ++q){
    int colc = (wid*2+q)*16 + lr;
    float bias = b2[colc];
    float v = 0.f;
    #pragma unroll
    for (int mf=0; mf<2; ++mf){
      int rbase = tile*32 + mf*16 + lk*4;
      #pragma unroll
      for (int r=0;r<4;++r){
        float val = fmaxf(acc[mf][q][r] + bias, 0.f);
        if (rbase + r < Nk) v += val;
      }
    }
    v += __shfl_xor(v, 16);
    v += __shfl_xor(v, 32);
    if (lane < 16) atomicAdd(&pooled[b*Hk + colc], v);
  }
}

__global__ void k7_final(const float* __restrict__ pooled, const float* __restrict__ Wro1,
                         const float* __restrict__ bro1, const float* __restrict__ Wro2,
                         const float* __restrict__ bro2, float* __restrict__ out){
  int b = blockIdx.x, t = threadIdx.x;
  __shared__ float pool[128];
  __shared__ float hid[128];
  pool[t] = pooled[b*Hk + t] * (1.0f/(float)Nk);
  __syncthreads();
  float s = bro1[t];
  for (int d=0; d<128; ++d) s += Wro1[t*128+d]*pool[d];
  hid[t] = fmaxf(s, 0.f);
  __syncthreads();
  if (t < Zk){
    float s2 = bro2[t];
    for (int d=0; d<128; ++d) s2 += Wro2[t*128+d]*hid[d];
    out[b*Zk + t] = s2;
  }
}

extern "C" void kernel_launch(void* const* d_in, const int* in_sizes, int n_in,
                              void* d_out, int out_size, void* d_ws, size_t ws_size,
                              hipStream_t stream) {
  const float* x    = (const float*)d_in[0];
  const int*   ei   = (const int*)d_in[1];
  const float* W1l  = (const float*)d_in[2];
  const float* b1   = (const float*)d_in[3];
  const float* W1r  = (const float*)d_in[4];
  const float* W2l  = (const float*)d_in[5];
  const float* b2   = (const float*)d_in[6];
  const float* W2r  = (const float*)d_in[7];
  const float* Wro1 = (const float*)d_in[8];
  const float* bro1 = (const float*)d_in[9];
  const float* Wro2 = (const float*)d_in[10];
  const float* bro2 = (const float*)d_in[11];
  float* out = (float*)d_out;

  // workspace layout (bytes, 256-aligned)
  char* ws = (char*)d_ws;
  int*   cur    = (int*)(ws + 0);              // 40000
  float* pooled = (float*)(ws + 40448);        // 4096
  __hip_bfloat16* wbt = (__hip_bfloat16*)(ws + 44544);    // 65536
  int*   csrsrc = (int*)(ws + 110080);         // 10000*64*4 = 2560000
  float* agg1   = (float*)(ws + 2670080);      // 320000
  __hip_bfloat16* h1 = (__hip_bfloat16*)(ws + 2990336);   // 8*10000*128*2 = 20480000

  k0_init<<<dim3(128), 256, 0, stream>>>(W2l, W2r, wbt, cur, pooled);
  k3_fill<<<dim3((Ek+255)/256), 256, 0, stream>>>(ei, cur, csrsrc);
  k4_agg1<<<dim3((Nk+255)/256, Bk), 256, 0, stream>>>(x, cur, csrsrc, agg1);
  kA_h1<<<dim3(2500, Bk), 256, 0, stream>>>(x, agg1, W1l, b1, W1r, h1);
  kB_fused<<<dim3(Bk, NTILES), 256, 0, stream>>>(h1, cur, csrsrc, wbt, b2, pooled);
  k7_final<<<dim3(Bk), 128, 0, stream>>>(pooled, Wro1, bro1, Wro2, bro2, out);
}

// Round 7
// 108.660 us; speedup vs baseline: 1.2184x; 1.2184x over previous
//
#include <hip/hip_runtime.h>
#include <hip/hip_bf16.h>

// Problem constants
#define Bk 8
#define Nk 10000
#define Ek 160000
#define Hk 128
#define Zk 64
#define CAPk 64      // bucket-CSR capacity; deg ~ Poisson(16), P(deg>=64) ~ 0
#define NTILES 313   // ceil(10000/32)
#define NROWS 10016  // h1 rows per batch (incl. zero rows; row Nk = gather pad target)

typedef float f32x4 __attribute__((ext_vector_type(4)));
typedef float f32x2 __attribute__((ext_vector_type(2)));
typedef short s16x8 __attribute__((ext_vector_type(8)));

__device__ inline f32x2 pk_add(f32x2 a, f32x2 b){
  f32x2 d; asm("v_pk_add_f32 %0, %1, %2" : "=v"(d) : "v"(a), "v"(b)); return d;
}
__device__ inline f32x2 bf2_to_f32x2(unsigned v){
  f32x2 r; r.x = __uint_as_float(v<<16); r.y = __uint_as_float(v & 0xffff0000u); return r;
}
__device__ inline unsigned pack_bf2(float lo, float hi){
  __hip_bfloat162 p; p.x = __float2bfloat16(lo); p.y = __float2bfloat16(hi);
  return *(unsigned*)&p;
}

// init: pack WBT (128x256 bf16: [W2l | W2r] rows), zero cur + pooled
__global__ __launch_bounds__(256) void k0_init(const float* __restrict__ W2l, const float* __restrict__ W2r,
                                               __hip_bfloat16* __restrict__ wbt, int* __restrict__ cur,
                                               float* __restrict__ pooled){
  int t = blockIdx.x*256 + threadIdx.x;
  if (t < 128*256){
    int o = t >> 8, k = t & 255;
    float v = (k < 128) ? W2l[o*128+k] : W2r[o*128+(k-128)];
    wbt[t] = __float2bfloat16(v);
  }
  if (t < Nk) cur[t] = 0;
  if (t < Bk*Hk) pooled[t] = 0.f;
}

// bucket-CSR fill: csrsrc[d*CAP + p] = src, cur[d] = degree
__global__ void k3_fill(const int* __restrict__ ei, int* __restrict__ cur, int* __restrict__ csrsrc){
  int e = blockIdx.x*blockDim.x + threadIdx.x;
  if (e < Ek){
    int s = ei[e], d = ei[Ek+e];
    int p = atomicAdd(&cur[d], 1);
    if (p < CAPk) csrsrc[d*CAPk + p] = s;
  }
}

// Fused agg1 + H1: one wave per node. Lane k gathers edge k's x (exec-masked),
// 6-shfl butterfly -> agg1 in-register -> h1 row = relu(agg1*w1l + x_i*w1r + b1)
// stored bf16 (dword/lane, coalesced). Also writes csrsrc pad slots [deg,deg4)
// = Nk for kB's quad loads, and zero h1 rows for i in [Nk, NROWS).
__global__ __launch_bounds__(256) void k45_h1(const float* __restrict__ x, const int* __restrict__ cur,
                        int* __restrict__ csrsrc,
                        const float* __restrict__ W1l, const float* __restrict__ b1,
                        const float* __restrict__ W1r, __hip_bfloat16* __restrict__ h1){
  int i = blockIdx.x*4 + (threadIdx.x>>6);
  int lane = threadIdx.x & 63;
  if (i >= Nk){
    if (i < NROWS){
      #pragma unroll
      for (int b=0;b<Bk;b++)
        *(unsigned*)((void*)(h1 + ((size_t)b*NROWS + i)*128 + 2*lane)) = 0u;
    }
    return;
  }
  float2 wl = *(const float2*)(W1l + 2*lane);
  float2 wr = *(const float2*)(W1r + 2*lane);
  float2 bb = *(const float2*)(b1  + 2*lane);
  int degc = cur[i];
  int deg = min(degc, CAPk);
  int deg4 = (deg + 3) & ~3;
  int* col = csrsrc + (size_t)i*CAPk;
  int j = 0;
  bool havej = (lane < deg);
  if (havej) j = col[lane];
  if (lane >= deg && lane < deg4) col[lane] = Nk;   // pad for kB
  float inv = 1.f/fmaxf((float)degc, 1.f);

  float xx[Bk];
  #pragma unroll
  for (int b=0;b<Bk;b++){
    float v = 0.f;
    if (havej) v = x[b*Nk + j];
    xx[b] = v;
  }
  #pragma unroll
  for (int b=0;b<Bk;b++){
    float s = xx[b];
    s += __shfl_xor(s, 1);  s += __shfl_xor(s, 2);  s += __shfl_xor(s, 4);
    s += __shfl_xor(s, 8);  s += __shfl_xor(s, 16); s += __shfl_xor(s, 32);
    float a  = s * inv;
    float xi = x[b*Nk + i];
    float v0 = fmaxf(fmaf(a, wl.x, fmaf(xi, wr.x, bb.x)), 0.f);
    float v1 = fmaxf(fmaf(a, wl.y, fmaf(xi, wr.y, bb.y)), 0.f);
    *(unsigned*)((void*)(h1 + ((size_t)b*NROWS + i)*128 + 2*lane)) = pack_bf2(v0, v1);
  }
}

__device__ inline void mfma_bf16(f32x4& d, s16x8 a, s16x8 b){
  asm("v_mfma_f32_16x16x32_bf16 %0, %1, %2, %0" : "+v"(d) : "v"(a), "v"(b));
}

// Fused layer-2: agg2 gather (neighbor-mean of H1 rows) -> LDS A-tile [agg2|h1]
// 32x256 swizzled -> MFMA vs wbt -> relu+bias -> column-sum -> atomic pooled.
// Gather: 4 edges per wave-load (lane group g of 16 covers edge k4+g's full
// 256 B row via dwordx4), pads hit zero row Nk; 2-step butterfly folds groups.
// grid dim3(8, NTILES): batch = blockIdx.x == XCD -> per-XCD L2-resident H1.
__global__ __launch_bounds__(256) void kB_fused(const __hip_bfloat16* __restrict__ h1,
                        const int* __restrict__ cur, const int* __restrict__ csrsrc,
                        const __hip_bfloat16* __restrict__ wbt, const float* __restrict__ b2,
                        float* __restrict__ pooled){
  __shared__ char At[32*512];   // 32 rows x 256 bf16, XOR-swizzled
  int b = blockIdx.x, tile = blockIdx.y;
  int wid = threadIdx.x >> 6, lane = threadIdx.x & 63;
  int g = lane >> 4, l4 = lane & 15;
  const __hip_bfloat16* h1b = h1 + (size_t)b*NROWS*128;

  // phase 1: each wave aggregates 8 rows
  for (int c=0;c<8;c++){
    int r = wid*8 + c;
    int i = tile*32 + r;
    f32x2 acc0 = {0.f,0.f}, acc1 = {0.f,0.f}, acc2 = {0.f,0.f}, acc3 = {0.f,0.f};
    float inv = 0.f;
    if (i < Nk){
      int degc = cur[i];
      int deg = min(degc, CAPk);
      int deg4 = (deg + 3) & ~3;
      const int* col = csrsrc + (size_t)i*CAPk;
      #pragma unroll 2
      for (int k4=0; k4<deg4; k4+=4){
        int j = col[k4 + g];                       // 4 distinct, L1-broadcast
        uint4 v = *(const uint4*)((const void*)(h1b + (size_t)j*128 + l4*8));
        acc0 = pk_add(acc0, bf2_to_f32x2(v.x));
        acc1 = pk_add(acc1, bf2_to_f32x2(v.y));
        acc2 = pk_add(acc2, bf2_to_f32x2(v.z));
        acc3 = pk_add(acc3, bf2_to_f32x2(v.w));
      }
      inv = 1.f/fmaxf((float)degc, 1.f);
    }
    // fold the 4 lane-groups (xor 16, 32)
    #pragma unroll
    for (int m=16; m<=32; m<<=1){
      acc0.x += __shfl_xor(acc0.x, m); acc0.y += __shfl_xor(acc0.y, m);
      acc1.x += __shfl_xor(acc1.x, m); acc1.y += __shfl_xor(acc1.y, m);
      acc2.x += __shfl_xor(acc2.x, m); acc2.y += __shfl_xor(acc2.y, m);
      acc3.x += __shfl_xor(acc3.x, m); acc3.y += __shfl_xor(acc3.y, m);
    }
    unsigned swz = (unsigned)((r & 7) << 4);
    if (g == 0){
      uint4 outv;
      outv.x = pack_bf2(acc0.x*inv, acc0.y*inv);
      outv.y = pack_bf2(acc1.x*inv, acc1.y*inv);
      outv.z = pack_bf2(acc2.x*inv, acc2.y*inv);
      outv.w = pack_bf2(acc3.x*inv, acc3.y*inv);
      *(uint4*)(At + r*512 + ((unsigned)(l4*16) ^ swz)) = outv;
    } else if (g == 1){
      uint4 sv = *(const uint4*)((const void*)(h1b + (size_t)i*128 + l4*8)); // rows < NROWS always valid
      *(uint4*)(At + r*512 + ((unsigned)(256 + l4*16) ^ swz)) = sv;
    }
  }
  __syncthreads();

  // phase 2: GEMM 32x256 @ 256x128; wave w -> cols 32w..32w+31
  int lr = lane & 15, lk = lane >> 4;
  f32x4 acc[2][2];
  #pragma unroll
  for (int mf=0; mf<2; ++mf)
    #pragma unroll
    for (int q=0; q<2; ++q) acc[mf][q] = (f32x4){0.f,0.f,0.f,0.f};

  unsigned rsw = (unsigned)((lr & 7) << 4);
  #pragma unroll
  for (int kk=0; kk<8; ++kk){
    unsigned cb = kk*64 + lk*16;
    s16x8 a0 = *(const s16x8*)(At + lr*512      + (cb ^ rsw));
    s16x8 a1 = *(const s16x8*)(At + (16+lr)*512 + (cb ^ rsw));
    #pragma unroll
    for (int q=0; q<2; ++q){
      int nf = wid*2 + q;
      s16x8 bfr = *(const s16x8*)(const void*)(wbt + (nf*16+lr)*256 + kk*32 + lk*8);
      mfma_bf16(acc[0][q], a0, bfr);
      mfma_bf16(acc[1][q], a1, bfr);
    }
  }

  // epilogue: relu(acc + b2), mask pad rows, column-reduce, atomic into pooled
  #pragma unroll
  for (int q=0; q<2; ++q){
    int colc = (wid*2+q)*16 + lr;
    float bias = b2[colc];
    float v = 0.f;
    #pragma unroll
    for (int mf=0; mf<2; ++mf){
      int rbase = tile*32 + mf*16 + lk*4;
      #pragma unroll
      for (int r=0;r<4;++r){
        float val = fmaxf(acc[mf][q][r] + bias, 0.f);
        if (rbase + r < Nk) v += val;
      }
    }
    v += __shfl_xor(v, 16);
    v += __shfl_xor(v, 32);
    if (lane < 16) atomicAdd(&pooled[b*Hk + colc], v);
  }
}

__global__ void k7_final(const float* __restrict__ pooled, const float* __restrict__ Wro1,
                         const float* __restrict__ bro1, const float* __restrict__ Wro2,
                         const float* __restrict__ bro2, float* __restrict__ out){
  int b = blockIdx.x, t = threadIdx.x;
  __shared__ float pool[128];
  __shared__ float hid[128];
  pool[t] = pooled[b*Hk + t] * (1.0f/(float)Nk);
  __syncthreads();
  float s = bro1[t];
  for (int d=0; d<128; ++d) s += Wro1[t*128+d]*pool[d];
  hid[t] = fmaxf(s, 0.f);
  __syncthreads();
  if (t < Zk){
    float s2 = bro2[t];
    for (int d=0; d<128; ++d) s2 += Wro2[t*128+d]*hid[d];
    out[b*Zk + t] = s2;
  }
}

extern "C" void kernel_launch(void* const* d_in, const int* in_sizes, int n_in,
                              void* d_out, int out_size, void* d_ws, size_t ws_size,
                              hipStream_t stream) {
  const float* x    = (const float*)d_in[0];
  const int*   ei   = (const int*)d_in[1];
  const float* W1l  = (const float*)d_in[2];
  const float* b1   = (const float*)d_in[3];
  const float* W1r  = (const float*)d_in[4];
  const float* W2l  = (const float*)d_in[5];
  const float* b2   = (const float*)d_in[6];
  const float* W2r  = (const float*)d_in[7];
  const float* Wro1 = (const float*)d_in[8];
  const float* bro1 = (const float*)d_in[9];
  const float* Wro2 = (const float*)d_in[10];
  const float* bro2 = (const float*)d_in[11];
  float* out = (float*)d_out;

  // workspace layout (bytes, 256-aligned)
  char* ws = (char*)d_ws;
  int*   cur    = (int*)(ws + 0);              // 40000
  float* pooled = (float*)(ws + 40448);        // 4096
  __hip_bfloat16* wbt = (__hip_bfloat16*)(ws + 44544);    // 65536
  int*   csrsrc = (int*)(ws + 110080);         // 10000*64*4 = 2560000
  __hip_bfloat16* h1 = (__hip_bfloat16*)(ws + 2670080);   // 8*10016*128*2 = 20512768

  k0_init<<<dim3(128), 256, 0, stream>>>(W2l, W2r, wbt, cur, pooled);
  k3_fill<<<dim3((Ek+255)/256), 256, 0, stream>>>(ei, cur, csrsrc);
  k45_h1<<<dim3(2504), 256, 0, stream>>>(x, cur, csrsrc, W1l, b1, W1r, h1);
  kB_fused<<<dim3(Bk, NTILES), 256, 0, stream>>>(h1, cur, csrsrc, wbt, b2, pooled);
  k7_final<<<dim3(Bk), 128, 0, stream>>>(pooled, Wro1, bro1, Wro2, bro2, out);
}

// Round 8
// 101.205 us; speedup vs baseline: 1.3082x; 1.0737x over previous
//
#include <hip/hip_runtime.h>
#include <hip/hip_bf16.h>

// Problem constants
#define Bk 8
#define Nk 10000
#define Ek 160000
#define Hk 128
#define Zk 64
#define CAPk 64      // bucket-CSR capacity; deg ~ Poisson(16), P(deg>=64) ~ 0
#define NTILES 313   // ceil(10000/32)
#define NROWS 10016  // h1/csr rows per batch (incl. zero rows; rows >= Nk are zero)

typedef float f32x4 __attribute__((ext_vector_type(4)));
typedef float f32x2 __attribute__((ext_vector_type(2)));
typedef short s16x8 __attribute__((ext_vector_type(8)));
typedef unsigned u32x4 __attribute__((ext_vector_type(4)));

__device__ inline f32x2 pk_add(f32x2 a, f32x2 b){
  f32x2 d; asm("v_pk_add_f32 %0, %1, %2" : "=v"(d) : "v"(a), "v"(b)); return d;
}
__device__ inline f32x2 bf2_to_f32x2(unsigned v){
  f32x2 r; r.x = __uint_as_float(v<<16); r.y = __uint_as_float(v & 0xffff0000u); return r;
}
__device__ inline unsigned pack_bf2(float lo, float hi){
  __hip_bfloat162 p; p.x = __float2bfloat16(lo); p.y = __float2bfloat16(hi);
  return *(unsigned*)&p;
}

// init: pack WBT (128x256 bf16: [W2l | W2r] rows), zero cur + pooled
__global__ __launch_bounds__(256) void k0_init(const float* __restrict__ W2l, const float* __restrict__ W2r,
                                               __hip_bfloat16* __restrict__ wbt, int* __restrict__ cur,
                                               float* __restrict__ pooled){
  int t = blockIdx.x*256 + threadIdx.x;
  if (t < 128*256){
    int o = t >> 8, k = t & 255;
    float v = (k < 128) ? W2l[o*128+k] : W2r[o*128+(k-128)];
    wbt[t] = __float2bfloat16(v);
  }
  if (t < Nk) cur[t] = 0;
  if (t < Bk*Hk) pooled[t] = 0.f;
}

// bucket-CSR fill: csrsrc[d*CAP + p] = src, cur[d] = degree
__global__ void k3_fill(const int* __restrict__ ei, int* __restrict__ cur, int* __restrict__ csrsrc){
  int e = blockIdx.x*blockDim.x + threadIdx.x;
  if (e < Ek){
    int s = ei[e], d = ei[Ek+e];
    int p = atomicAdd(&cur[d], 1);
    if (p < CAPk) csrsrc[d*CAPk + p] = s;
  }
}

// Fused agg1 + H1: one wave per node. Lane k gathers edge k's x (exec-masked),
// 6-shfl butterfly -> agg1 in-register -> h1 row = relu(agg1*w1l + x_i*w1r + b1)
// stored bf16. Writes csrsrc pad slots [deg,deg4) = Nk; zero rows for i >= Nk.
__global__ __launch_bounds__(256) void k45_h1(const float* __restrict__ x, const int* __restrict__ cur,
                        int* __restrict__ csrsrc,
                        const float* __restrict__ W1l, const float* __restrict__ b1,
                        const float* __restrict__ W1r, __hip_bfloat16* __restrict__ h1){
  int i = blockIdx.x*4 + (threadIdx.x>>6);
  int lane = threadIdx.x & 63;
  if (i >= Nk){
    if (i < NROWS){
      #pragma unroll
      for (int b=0;b<Bk;b++)
        *(unsigned*)((void*)(h1 + ((size_t)b*NROWS + i)*128 + 2*lane)) = 0u;
    }
    return;
  }
  float2 wl = *(const float2*)(W1l + 2*lane);
  float2 wr = *(const float2*)(W1r + 2*lane);
  float2 bb = *(const float2*)(b1  + 2*lane);
  int degc = cur[i];
  int deg = min(degc, CAPk);
  int deg4 = (deg + 3) & ~3;
  int* col = csrsrc + (size_t)i*CAPk;
  int j = 0;
  bool havej = (lane < deg);
  if (havej) j = col[lane];
  if (lane >= deg && lane < deg4) col[lane] = Nk;   // pad for kB
  float inv = 1.f/fmaxf((float)degc, 1.f);

  float xx[Bk];
  #pragma unroll
  for (int b=0;b<Bk;b++){
    float v = 0.f;
    if (havej) v = x[b*Nk + j];
    xx[b] = v;
  }
  #pragma unroll
  for (int b=0;b<Bk;b++){
    float s = xx[b];
    s += __shfl_xor(s, 1);  s += __shfl_xor(s, 2);  s += __shfl_xor(s, 4);
    s += __shfl_xor(s, 8);  s += __shfl_xor(s, 16); s += __shfl_xor(s, 32);
    float a  = s * inv;
    float xi = x[b*Nk + i];
    float v0 = fmaxf(fmaf(a, wl.x, fmaf(xi, wr.x, bb.x)), 0.f);
    float v1 = fmaxf(fmaf(a, wl.y, fmaf(xi, wr.y, bb.y)), 0.f);
    *(unsigned*)((void*)(h1 + ((size_t)b*NROWS + i)*128 + 2*lane)) = pack_bf2(v0, v1);
  }
}

__device__ inline void mfma_bf16(f32x4& d, s16x8 a, s16x8 b){
  asm("v_mfma_f32_16x16x32_bf16 %0, %1, %2, %0" : "+v"(d) : "v"(a), "v"(b));
}

// Fused layer-2: csr tile staged to LDS (nontemporal), agg2 gather with 2 rows
// interleaved per wave (8 edges in flight), LDS A-tile [agg2|h1] -> MFMA ->
// relu+bias -> column-sum -> atomic pooled. batch = blockIdx.x == XCD.
__global__ __launch_bounds__(256) void kB_fused(const __hip_bfloat16* __restrict__ h1,
                        const int* __restrict__ cur, const int* __restrict__ csrsrc,
                        const __hip_bfloat16* __restrict__ wbt, const float* __restrict__ b2,
                        float* __restrict__ pooled){
  __shared__ char At[32*512];        // 32 rows x 256 bf16, XOR-swizzled
  __shared__ int scol[32*CAPk];      // 8 KB csr tile
  __shared__ int sdeg[32];
  int b = blockIdx.x, tile = blockIdx.y;
  int tid = threadIdx.x;
  int wid = tid >> 6, lane = tid & 63;
  int g = lane >> 4, l4 = lane & 15;
  const __hip_bfloat16* h1b = h1 + (size_t)b*NROWS*128;

  // stage csr tile (nontemporal: streaming, keep L2 for h1)
  {
    const u32x4* src = (const u32x4*)(csrsrc + (size_t)tile*32*CAPk);
    u32x4* dst = (u32x4*)scol;
    dst[tid]       = __builtin_nontemporal_load(src + tid);
    dst[256 + tid] = __builtin_nontemporal_load(src + 256 + tid);
    if (tid < 32){
      int i = tile*32 + tid;
      sdeg[tid] = (i < Nk) ? cur[i] : 0;
    }
  }
  __syncthreads();

  // phase 1: each wave aggregates 8 rows, 2 at a time (independent chains)
  for (int c=0;c<4;c++){
    int rA = wid*8 + 2*c, rB = rA + 1;
    int iA = tile*32 + rA, iB = iA + 1;
    int dcA = sdeg[rA], dcB = sdeg[rB];
    int d4A = (min(dcA,CAPk)+3)&~3, d4B = (min(dcB,CAPk)+3)&~3;

    // self rows: always valid (zero rows beyond Nk); issue early
    u32x4 svA = {0,0,0,0}, svB = {0,0,0,0};
    if (g == 1) svA = *(const u32x4*)((const void*)(h1b + (size_t)iA*128 + l4*8));
    if (g == 3) svB = *(const u32x4*)((const void*)(h1b + (size_t)iB*128 + l4*8));

    f32x2 aA0={0.f,0.f}, aA1={0.f,0.f}, aA2={0.f,0.f}, aA3={0.f,0.f};
    f32x2 aB0={0.f,0.f}, aB1={0.f,0.f}, aB2={0.f,0.f}, aB3={0.f,0.f};
    int mx = max(d4A, d4B);
    for (int k4=0; k4<mx; k4+=4){
      if (k4 < d4A){
        int j = scol[rA*CAPk + k4 + g];
        u32x4 v = *(const u32x4*)((const void*)(h1b + (size_t)j*128 + l4*8));
        aA0 = pk_add(aA0, bf2_to_f32x2(v.x));
        aA1 = pk_add(aA1, bf2_to_f32x2(v.y));
        aA2 = pk_add(aA2, bf2_to_f32x2(v.z));
        aA3 = pk_add(aA3, bf2_to_f32x2(v.w));
      }
      if (k4 < d4B){
        int j = scol[rB*CAPk + k4 + g];
        u32x4 v = *(const u32x4*)((const void*)(h1b + (size_t)j*128 + l4*8));
        aB0 = pk_add(aB0, bf2_to_f32x2(v.x));
        aB1 = pk_add(aB1, bf2_to_f32x2(v.y));
        aB2 = pk_add(aB2, bf2_to_f32x2(v.z));
        aB3 = pk_add(aB3, bf2_to_f32x2(v.w));
      }
    }
    // fold the 4 lane-groups (xor 16, 32)
    #pragma unroll
    for (int m=16; m<=32; m<<=1){
      aA0.x += __shfl_xor(aA0.x, m); aA0.y += __shfl_xor(aA0.y, m);
      aA1.x += __shfl_xor(aA1.x, m); aA1.y += __shfl_xor(aA1.y, m);
      aA2.x += __shfl_xor(aA2.x, m); aA2.y += __shfl_xor(aA2.y, m);
      aA3.x += __shfl_xor(aA3.x, m); aA3.y += __shfl_xor(aA3.y, m);
      aB0.x += __shfl_xor(aB0.x, m); aB0.y += __shfl_xor(aB0.y, m);
      aB1.x += __shfl_xor(aB1.x, m); aB1.y += __shfl_xor(aB1.y, m);
      aB2.x += __shfl_xor(aB2.x, m); aB2.y += __shfl_xor(aB2.y, m);
      aB3.x += __shfl_xor(aB3.x, m); aB3.y += __shfl_xor(aB3.y, m);
    }
    float invA = 1.f/fmaxf((float)dcA, 1.f);
    float invB = 1.f/fmaxf((float)dcB, 1.f);
    unsigned swzA = (unsigned)((rA & 7) << 4);
    unsigned swzB = (unsigned)((rB & 7) << 4);
    if (g == 0){
      u32x4 outv;
      outv.x = pack_bf2(aA0.x*invA, aA0.y*invA);
      outv.y = pack_bf2(aA1.x*invA, aA1.y*invA);
      outv.z = pack_bf2(aA2.x*invA, aA2.y*invA);
      outv.w = pack_bf2(aA3.x*invA, aA3.y*invA);
      *(u32x4*)(At + rA*512 + ((unsigned)(l4*16) ^ swzA)) = outv;
    } else if (g == 1){
      *(u32x4*)(At + rA*512 + ((unsigned)(256 + l4*16) ^ swzA)) = svA;
    } else if (g == 2){
      u32x4 outv;
      outv.x = pack_bf2(aB0.x*invB, aB0.y*invB);
      outv.y = pack_bf2(aB1.x*invB, aB1.y*invB);
      outv.z = pack_bf2(aB2.x*invB, aB2.y*invB);
      outv.w = pack_bf2(aB3.x*invB, aB3.y*invB);
      *(u32x4*)(At + rB*512 + ((unsigned)(l4*16) ^ swzB)) = outv;
    } else {
      *(u32x4*)(At + rB*512 + ((unsigned)(256 + l4*16) ^ swzB)) = svB;
    }
  }
  __syncthreads();

  // phase 2: GEMM 32x256 @ 256x128; wave w -> cols 32w..32w+31
  int lr = lane & 15, lk = lane >> 4;
  f32x4 acc[2][2];
  #pragma unroll
  for (int mf=0; mf<2; ++mf)
    #pragma unroll
    for (int q=0; q<2; ++q) acc[mf][q] = (f32x4){0.f,0.f,0.f,0.f};

  unsigned rsw = (unsigned)((lr & 7) << 4);
  #pragma unroll
  for (int kk=0; kk<8; ++kk){
    unsigned cb = kk*64 + lk*16;
    s16x8 a0 = *(const s16x8*)(At + lr*512      + (cb ^ rsw));
    s16x8 a1 = *(const s16x8*)(At + (16+lr)*512 + (cb ^ rsw));
    #pragma unroll
    for (int q=0; q<2; ++q){
      int nf = wid*2 + q;
      s16x8 bfr = *(const s16x8*)(const void*)(wbt + (nf*16+lr)*256 + kk*32 + lk*8);
      mfma_bf16(acc[0][q], a0, bfr);
      mfma_bf16(acc[1][q], a1, bfr);
    }
  }

  // epilogue: relu(acc + b2), mask pad rows, column-reduce, atomic into pooled
  #pragma unroll
  for (int q=0; q<2; ++q){
    int colc = (wid*2+q)*16 + lr;
    float bias = b2[colc];
    float v = 0.f;
    #pragma unroll
    for (int mf=0; mf<2; ++mf){
      int rbase = tile*32 + mf*16 + lk*4;
      #pragma unroll
      for (int r=0;r<4;++r){
        float val = fmaxf(acc[mf][q][r] + bias, 0.f);
        if (rbase + r < Nk) v += val;
      }
    }
    v += __shfl_xor(v, 16);
    v += __shfl_xor(v, 32);
    if (lane < 16) atomicAdd(&pooled[b*Hk + colc], v);
  }
}

__global__ void k7_final(const float* __restrict__ pooled, const float* __restrict__ Wro1,
                         const float* __restrict__ bro1, const float* __restrict__ Wro2,
                         const float* __restrict__ bro2, float* __restrict__ out){
  int b = blockIdx.x, t = threadIdx.x;
  __shared__ float pool[128];
  __shared__ float hid[128];
  pool[t] = pooled[b*Hk + t] * (1.0f/(float)Nk);
  __syncthreads();
  float s = bro1[t];
  for (int d=0; d<128; ++d) s += Wro1[t*128+d]*pool[d];
  hid[t] = fmaxf(s, 0.f);
  __syncthreads();
  if (t < Zk){
    float s2 = bro2[t];
    for (int d=0; d<128; ++d) s2 += Wro2[t*128+d]*hid[d];
    out[b*Zk + t] = s2;
  }
}

extern "C" void kernel_launch(void* const* d_in, const int* in_sizes, int n_in,
                              void* d_out, int out_size, void* d_ws, size_t ws_size,
                              hipStream_t stream) {
  const float* x    = (const float*)d_in[0];
  const int*   ei   = (const int*)d_in[1];
  const float* W1l  = (const float*)d_in[2];
  const float* b1   = (const float*)d_in[3];
  const float* W1r  = (const float*)d_in[4];
  const float* W2l  = (const float*)d_in[5];
  const float* b2   = (const float*)d_in[6];
  const float* W2r  = (const float*)d_in[7];
  const float* Wro1 = (const float*)d_in[8];
  const float* bro1 = (const float*)d_in[9];
  const float* Wro2 = (const float*)d_in[10];
  const float* bro2 = (const float*)d_in[11];
  float* out = (float*)d_out;

  // workspace layout (bytes, 256-aligned)
  char* ws = (char*)d_ws;
  int*   cur    = (int*)(ws + 0);              // 40000
  float* pooled = (float*)(ws + 40448);        // 4096
  __hip_bfloat16* wbt = (__hip_bfloat16*)(ws + 44544);    // 65536
  int*   csrsrc = (int*)(ws + 110080);         // 10016*64*4 = 2564096
  __hip_bfloat16* h1 = (__hip_bfloat16*)(ws + 2674176);   // 8*10016*128*2 = 20512768

  k0_init<<<dim3(128), 256, 0, stream>>>(W2l, W2r, wbt, cur, pooled);
  k3_fill<<<dim3((Ek+255)/256), 256, 0, stream>>>(ei, cur, csrsrc);
  k45_h1<<<dim3(2504), 256, 0, stream>>>(x, cur, csrsrc, W1l, b1, W1r, h1);
  kB_fused<<<dim3(Bk, NTILES), 256, 0, stream>>>(h1, cur, csrsrc, wbt, b2, pooled);
  k7_final<<<dim3(Bk), 128, 0, stream>>>(pooled, Wro1, bro1, Wro2, bro2, out);
}

// Round 10
// 96.236 us; speedup vs baseline: 1.3757x; 1.0516x over previous
//
#include <hip/hip_runtime.h>
#include <hip/hip_bf16.h>

// Problem constants
#define Bk 8
#define Nk 10000
#define Ek 160000
#define Hk 128
#define Zk 64
#define CAPk 64      // bucket-CSR capacity; deg ~ Poisson(16), P(deg>=64) ~ 0
#define NTILES 313   // ceil(10000/32)
#define NROWS 10016  // h1/csr rows per batch (incl. zero rows; rows >= Nk are zero)

typedef float f32x4 __attribute__((ext_vector_type(4)));
typedef float f32x2 __attribute__((ext_vector_type(2)));
typedef short s16x8 __attribute__((ext_vector_type(8)));
typedef unsigned u32x4 __attribute__((ext_vector_type(4)));

__device__ inline f32x2 pk_add(f32x2 a, f32x2 b){
  f32x2 d; asm("v_pk_add_f32 %0, %1, %2" : "=v"(d) : "v"(a), "v"(b)); return d;
}
__device__ inline f32x2 bf2_to_f32x2(unsigned v){
  f32x2 r; r.x = __uint_as_float(v<<16); r.y = __uint_as_float(v & 0xffff0000u); return r;
}
__device__ inline unsigned pack_bf2(float lo, float hi){
  __hip_bfloat162 p; p.x = __float2bfloat16(lo); p.y = __float2bfloat16(hi);
  return *(unsigned*)&p;
}

// init: pack WBT (128x256 bf16: [W2l | W2r] rows), zero cur + pooled
__global__ __launch_bounds__(256) void k0_init(const float* __restrict__ W2l, const float* __restrict__ W2r,
                                               __hip_bfloat16* __restrict__ wbt, int* __restrict__ cur,
                                               float* __restrict__ pooled){
  int t = blockIdx.x*256 + threadIdx.x;
  if (t < 128*256){
    int o = t >> 8, k = t & 255;
    float v = (k < 128) ? W2l[o*128+k] : W2r[o*128+(k-128)];
    wbt[t] = __float2bfloat16(v);
  }
  if (t < Nk) cur[t] = 0;
  if (t < Bk*Hk) pooled[t] = 0.f;
}

// bucket-CSR fill: csrsrc[d*CAP + p] = src, cur[d] = degree
__global__ void k3_fill(const int* __restrict__ ei, int* __restrict__ cur, int* __restrict__ csrsrc){
  int e = blockIdx.x*blockDim.x + threadIdx.x;
  if (e < Ek){
    int s = ei[e], d = ei[Ek+e];
    int p = atomicAdd(&cur[d], 1);
    if (p < CAPk) csrsrc[d*CAPk + p] = s;
  }
}

// Fused agg1 + H1: one wave per node. Lane k gathers edge k's x (exec-masked),
// 6-shfl butterfly -> agg1 in-register -> h1 row = relu(agg1*w1l + x_i*w1r + b1)
// stored bf16. Zero rows for i in [Nk, NROWS).
__global__ __launch_bounds__(256) void k45_h1(const float* __restrict__ x, const int* __restrict__ cur,
                        const int* __restrict__ csrsrc,
                        const float* __restrict__ W1l, const float* __restrict__ b1,
                        const float* __restrict__ W1r, __hip_bfloat16* __restrict__ h1){
  int i = blockIdx.x*4 + (threadIdx.x>>6);
  int lane = threadIdx.x & 63;
  if (i >= Nk){
    if (i < NROWS){
      #pragma unroll
      for (int b=0;b<Bk;b++)
        *(unsigned*)((void*)(h1 + ((size_t)b*NROWS + i)*128 + 2*lane)) = 0u;
    }
    return;
  }
  float2 wl = *(const float2*)(W1l + 2*lane);
  float2 wr = *(const float2*)(W1r + 2*lane);
  float2 bb = *(const float2*)(b1  + 2*lane);
  int degc = cur[i];
  int deg = min(degc, CAPk);
  const int* col = csrsrc + (size_t)i*CAPk;
  int j = 0;
  bool havej = (lane < deg);
  if (havej) j = col[lane];
  float inv = 1.f/fmaxf((float)degc, 1.f);

  float xx[Bk];
  #pragma unroll
  for (int b=0;b<Bk;b++){
    float v = 0.f;
    if (havej) v = x[b*Nk + j];
    xx[b] = v;
  }
  #pragma unroll
  for (int b=0;b<Bk;b++){
    float s = xx[b];
    s += __shfl_xor(s, 1);  s += __shfl_xor(s, 2);  s += __shfl_xor(s, 4);
    s += __shfl_xor(s, 8);  s += __shfl_xor(s, 16); s += __shfl_xor(s, 32);
    float a  = s * inv;
    float xi = x[b*Nk + i];
    float v0 = fmaxf(fmaf(a, wl.x, fmaf(xi, wr.x, bb.x)), 0.f);
    float v1 = fmaxf(fmaf(a, wl.y, fmaf(xi, wr.y, bb.y)), 0.f);
    *(unsigned*)((void*)(h1 + ((size_t)b*NROWS + i)*128 + 2*lane)) = pack_bf2(v0, v1);
  }
}

__device__ inline void mfma_bf16(f32x4& d, s16x8 a, s16x8 b){
  asm("v_mfma_f32_16x16x32_bf16 %0, %1, %2, %0" : "+v"(d) : "v"(a), "v"(b));
}

// Fused layer-2: csr tile staged to LDS with PER-SLOT pad-patch (slot >= deg
// -> Nk, the zero row; covers intra-quad tails AND poison beyond deg), agg2
// gather with GROUP-OWNS-ROW structure: each 16-lane group owns one full
// 256 B row; 4 rows per wave in parallel, wave-uniform loop to the group-max
// trip count (pads hit the L1-hot zero row). No cross-group fold. Then LDS
// A-tile [agg2|h1] -> MFMA -> relu+bias -> column-sum -> atomic pooled.
// batch = blockIdx.x == XCD -> per-XCD L2-resident h1.
__global__ __launch_bounds__(256) void kB_fused(const __hip_bfloat16* __restrict__ h1,
                        const int* __restrict__ cur, const int* __restrict__ csrsrc,
                        const __hip_bfloat16* __restrict__ wbt, const float* __restrict__ b2,
                        float* __restrict__ pooled){
  __shared__ char At[32*512];        // 32 rows x 256 bf16, XOR-swizzled
  __shared__ int scol[32*CAPk];      // 8 KB csr tile (pad-patched)
  __shared__ int sdeg[32];
  int b = blockIdx.x, tile = blockIdx.y;
  int tid = threadIdx.x;
  int wid = tid >> 6, lane = tid & 63;
  int g = lane >> 4, l4 = lane & 15;
  const __hip_bfloat16* h1b = h1 + (size_t)b*NROWS*128;

  if (tid < 32){
    int i = tile*32 + tid;
    sdeg[tid] = (i < Nk) ? cur[i] : 0;
  }
  __syncthreads();

  // stage csr tile (nontemporal), per-slot patch: slot >= deg(row) -> Nk
  {
    const u32x4* src = (const u32x4*)(csrsrc + (size_t)tile*32*CAPk);
    u32x4* dst = (u32x4*)scol;
    #pragma unroll
    for (int h=0; h<2; ++h){
      int idx = h*256 + tid;
      u32x4 v = __builtin_nontemporal_load(src + idx);
      int row = idx >> 4;            // 16 quads per row
      int p = (idx & 15) * 4;        // slot within row (multiple of 4)
      int d = min(sdeg[row], CAPk);
      if (p+0 >= d) v.x = Nk;
      if (p+1 >= d) v.y = Nk;
      if (p+2 >= d) v.z = Nk;
      if (p+3 >= d) v.w = Nk;
      dst[idx] = v;
    }
  }
  __syncthreads();

  // phase 1: 4 rows per wave, group g owns row (wid*8 + c*4 + g) entirely
  #pragma unroll
  for (int c=0;c<2;c++){
    int rg = wid*8 + c*4 + g;
    int ig = tile*32 + rg;
    int dc = sdeg[rg];
    int d4 = (min(dc, CAPk) + 3) & ~3;
    int km = d4;
    km = max(km, __shfl_xor(km, 16));
    km = max(km, __shfl_xor(km, 32));   // wave-uniform trip count

    // self row early (always valid: zero rows beyond Nk)
    u32x4 sv = *(const u32x4*)((const void*)(h1b + (size_t)ig*128 + l4*8));

    f32x2 a0={0.f,0.f}, a1={0.f,0.f}, a2={0.f,0.f}, a3={0.f,0.f};
    const int* colg = scol + rg*CAPk;
    #pragma unroll 2
    for (int k=0; k<km; ++k){
      int j = colg[k];                 // pads -> Nk (zero row, L1-hot)
      u32x4 v = *(const u32x4*)((const void*)(h1b + (size_t)j*128 + l4*8));
      a0 = pk_add(a0, bf2_to_f32x2(v.x));
      a1 = pk_add(a1, bf2_to_f32x2(v.y));
      a2 = pk_add(a2, bf2_to_f32x2(v.z));
      a3 = pk_add(a3, bf2_to_f32x2(v.w));
    }
    float inv = 1.f/fmaxf((float)dc, 1.f);
    u32x4 outv;
    outv.x = pack_bf2(a0.x*inv, a0.y*inv);
    outv.y = pack_bf2(a1.x*inv, a1.y*inv);
    outv.z = pack_bf2(a2.x*inv, a2.y*inv);
    outv.w = pack_bf2(a3.x*inv, a3.y*inv);
    unsigned swz = (unsigned)((rg & 7) << 4);
    *(u32x4*)(At + rg*512 + ((unsigned)(l4*16) ^ swz))       = outv;
    *(u32x4*)(At + rg*512 + ((unsigned)(256 + l4*16) ^ swz)) = sv;
  }
  __syncthreads();

  // phase 2: GEMM 32x256 @ 256x128; wave w -> cols 32w..32w+31
  int lr = lane & 15, lk = lane >> 4;
  f32x4 acc[2][2];
  #pragma unroll
  for (int mf=0; mf<2; ++mf)
    #pragma unroll
    for (int q=0; q<2; ++q) acc[mf][q] = (f32x4){0.f,0.f,0.f,0.f};

  unsigned rsw = (unsigned)((lr & 7) << 4);
  #pragma unroll
  for (int kk=0; kk<8; ++kk){
    unsigned cb = kk*64 + lk*16;
    s16x8 a0 = *(const s16x8*)(At + lr*512      + (cb ^ rsw));
    s16x8 a1 = *(const s16x8*)(At + (16+lr)*512 + (cb ^ rsw));
    #pragma unroll
    for (int q=0; q<2; ++q){
      int nf = wid*2 + q;
      s16x8 bfr = *(const s16x8*)(const void*)(wbt + (nf*16+lr)*256 + kk*32 + lk*8);
      mfma_bf16(acc[0][q], a0, bfr);
      mfma_bf16(acc[1][q], a1, bfr);
    }
  }

  // epilogue: relu(acc + b2), mask pad rows, column-reduce, atomic into pooled
  #pragma unroll
  for (int q=0; q<2; ++q){
    int colc = (wid*2+q)*16 + lr;
    float bias = b2[colc];
    float v = 0.f;
    #pragma unroll
    for (int mf=0; mf<2; ++mf){
      int rbase = tile*32 + mf*16 + lk*4;
      #pragma unroll
      for (int r=0;r<4;++r){
        float val = fmaxf(acc[mf][q][r] + bias, 0.f);
        if (rbase + r < Nk) v += val;
      }
    }
    v += __shfl_xor(v, 16);
    v += __shfl_xor(v, 32);
    if (lane < 16) atomicAdd(&pooled[b*Hk + colc], v);
  }
}

__global__ void k7_final(const float* __restrict__ pooled, const float* __restrict__ Wro1,
                         const float* __restrict__ bro1, const float* __restrict__ Wro2,
                         const float* __restrict__ bro2, float* __restrict__ out){
  int b = blockIdx.x, t = threadIdx.x;
  __shared__ float pool[128];
  __shared__ float hid[128];
  pool[t] = pooled[b*Hk + t] * (1.0f/(float)Nk);
  __syncthreads();
  float s = bro1[t];
  for (int d=0; d<128; ++d) s += Wro1[t*128+d]*pool[d];
  hid[t] = fmaxf(s, 0.f);
  __syncthreads();
  if (t < Zk){
    float s2 = bro2[t];
    for (int d=0; d<128; ++d) s2 += Wro2[t*128+d]*hid[d];
    out[b*Zk + t] = s2;
  }
}

extern "C" void kernel_launch(void* const* d_in, const int* in_sizes, int n_in,
                              void* d_out, int out_size, void* d_ws, size_t ws_size,
                              hipStream_t stream) {
  const float* x    = (const float*)d_in[0];
  const int*   ei   = (const int*)d_in[1];
  const float* W1l  = (const float*)d_in[2];
  const float* b1   = (const float*)d_in[3];
  const float* W1r  = (const float*)d_in[4];
  const float* W2l  = (const float*)d_in[5];
  const float* b2   = (const float*)d_in[6];
  const float* W2r  = (const float*)d_in[7];
  const float* Wro1 = (const float*)d_in[8];
  const float* bro1 = (const float*)d_in[9];
  const float* Wro2 = (const float*)d_in[10];
  const float* bro2 = (const float*)d_in[11];
  float* out = (float*)d_out;

  // workspace layout (bytes, 256-aligned)
  char* ws = (char*)d_ws;
  int*   cur    = (int*)(ws + 0);              // 40000
  float* pooled = (float*)(ws + 40448);        // 4096
  __hip_bfloat16* wbt = (__hip_bfloat16*)(ws + 44544);    // 65536
  int*   csrsrc = (int*)(ws + 110080);         // 10016*64*4 = 2564096
  __hip_bfloat16* h1 = (__hip_bfloat16*)(ws + 2674176);   // 8*10016*128*2 = 20512768

  k0_init<<<dim3(128), 256, 0, stream>>>(W2l, W2r, wbt, cur, pooled);
  k3_fill<<<dim3((Ek+255)/256), 256, 0, stream>>>(ei, cur, csrsrc);
  k45_h1<<<dim3(2504), 256, 0, stream>>>(x, cur, csrsrc, W1l, b1, W1r, h1);
  kB_fused<<<dim3(Bk, NTILES), 256, 0, stream>>>(h1, cur, csrsrc, wbt, b2, pooled);
  k7_final<<<dim3(Bk), 128, 0, stream>>>(pooled, Wro1, bro1, Wro2, bro2, out);
}

// Round 11
// 87.082 us; speedup vs baseline: 1.5203x; 1.1051x over previous
//
#include <hip/hip_runtime.h>
#include <hip/hip_bf16.h>

// Problem constants
#define Bk 8
#define Nk 10000
#define Ek 160000
#define Hk 128
#define Zk 64
#define CAPk 64      // bucket-CSR capacity; deg ~ Poisson(16), P(deg>=64) ~ 0
#define NTILES 313   // ceil(10000/32)
#define NROWS 10016  // h1/csr rows per batch (incl. zero rows; rows >= Nk are zero)

typedef float f32x4 __attribute__((ext_vector_type(4)));
typedef float f32x2 __attribute__((ext_vector_type(2)));
typedef short s16x8 __attribute__((ext_vector_type(8)));
typedef unsigned u32x4 __attribute__((ext_vector_type(4)));

__device__ inline f32x2 pk_add(f32x2 a, f32x2 b){
  f32x2 d; asm("v_pk_add_f32 %0, %1, %2" : "=v"(d) : "v"(a), "v"(b)); return d;
}
__device__ inline f32x2 bf2_to_f32x2(unsigned v){
  f32x2 r; r.x = __uint_as_float(v<<16); r.y = __uint_as_float(v & 0xffff0000u); return r;
}
__device__ inline unsigned pack_bf2(float lo, float hi){
  __hip_bfloat162 p; p.x = __float2bfloat16(lo); p.y = __float2bfloat16(hi);
  return *(unsigned*)&p;
}

// init: pack WBT (128x256 bf16: [W2l | W2r] rows), zero cur + pooled
__global__ __launch_bounds__(256) void k0_init(const float* __restrict__ W2l, const float* __restrict__ W2r,
                                               __hip_bfloat16* __restrict__ wbt, int* __restrict__ cur,
                                               float* __restrict__ pooled){
  int t = blockIdx.x*256 + threadIdx.x;
  if (t < 128*256){
    int o = t >> 8, k = t & 255;
    float v = (k < 128) ? W2l[o*128+k] : W2r[o*128+(k-128)];
    wbt[t] = __float2bfloat16(v);
  }
  if (t < Nk) cur[t] = 0;
  if (t < Bk*Hk) pooled[t] = 0.f;
}

// bucket-CSR fill: csrsrc[d*CAP + p] = src, cur[d] = degree
__global__ void k3_fill(const int* __restrict__ ei, int* __restrict__ cur, int* __restrict__ csrsrc){
  int e = blockIdx.x*blockDim.x + threadIdx.x;
  if (e < Ek){
    int s = ei[e], d = ei[Ek+e];
    int p = atomicAdd(&cur[d], 1);
    if (p < CAPk) csrsrc[d*CAPk + p] = s;
  }
}

// Fused agg1 + H1: one wave per node. Lane k gathers edge k's x (exec-masked),
// 6-shfl butterfly -> agg1 in-register -> h1 row = relu(agg1*w1l + x_i*w1r + b1)
// stored bf16. Zero rows for i in [Nk, NROWS).
__global__ __launch_bounds__(256) void k45_h1(const float* __restrict__ x, const int* __restrict__ cur,
                        const int* __restrict__ csrsrc,
                        const float* __restrict__ W1l, const float* __restrict__ b1,
                        const float* __restrict__ W1r, __hip_bfloat16* __restrict__ h1){
  int i = blockIdx.x*4 + (threadIdx.x>>6);
  int lane = threadIdx.x & 63;
  if (i >= Nk){
    if (i < NROWS){
      #pragma unroll
      for (int b=0;b<Bk;b++)
        *(unsigned*)((void*)(h1 + ((size_t)b*NROWS + i)*128 + 2*lane)) = 0u;
    }
    return;
  }
  float2 wl = *(const float2*)(W1l + 2*lane);
  float2 wr = *(const float2*)(W1r + 2*lane);
  float2 bb = *(const float2*)(b1  + 2*lane);
  int degc = cur[i];
  int deg = min(degc, CAPk);
  const int* col = csrsrc + (size_t)i*CAPk;
  int j = 0;
  bool havej = (lane < deg);
  if (havej) j = col[lane];
  float inv = 1.f/fmaxf((float)degc, 1.f);

  float xx[Bk];
  #pragma unroll
  for (int b=0;b<Bk;b++){
    float v = 0.f;
    if (havej) v = x[b*Nk + j];
    xx[b] = v;
  }
  #pragma unroll
  for (int b=0;b<Bk;b++){
    float s = xx[b];
    s += __shfl_xor(s, 1);  s += __shfl_xor(s, 2);  s += __shfl_xor(s, 4);
    s += __shfl_xor(s, 8);  s += __shfl_xor(s, 16); s += __shfl_xor(s, 32);
    float a  = s * inv;
    float xi = x[b*Nk + i];
    float v0 = fmaxf(fmaf(a, wl.x, fmaf(xi, wr.x, bb.x)), 0.f);
    float v1 = fmaxf(fmaf(a, wl.y, fmaf(xi, wr.y, bb.y)), 0.f);
    *(unsigned*)((void*)(h1 + ((size_t)b*NROWS + i)*128 + 2*lane)) = pack_bf2(v0, v1);
  }
}

__device__ inline void mfma_bf16(f32x4& d, s16x8 a, s16x8 b){
  asm("v_mfma_f32_16x16x32_bf16 %0, %1, %2, %0" : "+v"(d) : "v"(a), "v"(b));
}

// Fused layer-2: csr tile staged to LDS with PER-SLOT pad-patch (slot >= deg
// -> Nk, the zero row), agg2 gather with GROUP-OWNS-ROW + explicit QUAD MLP:
// each k-step does one ds_read_b128 (4 j's) then 4 INDEPENDENT dwordx4 row
// loads, then unpacks all 4 (vmcnt stays >= 3 while unpacking -> 4 loads in
// flight per wave). Pads hit the L1-hot zero row. Then LDS A-tile [agg2|h1]
// -> MFMA -> relu+bias -> column-sum -> atomic pooled.
// batch = blockIdx.x == XCD -> per-XCD L2-resident h1.
__global__ __launch_bounds__(256) void kB_fused(const __hip_bfloat16* __restrict__ h1,
                        const int* __restrict__ cur, const int* __restrict__ csrsrc,
                        const __hip_bfloat16* __restrict__ wbt, const float* __restrict__ b2,
                        float* __restrict__ pooled){
  __shared__ char At[32*512];        // 32 rows x 256 bf16, XOR-swizzled
  __shared__ int scol[32*CAPk];      // 8 KB csr tile (pad-patched)
  __shared__ int sdeg[32];
  int b = blockIdx.x, tile = blockIdx.y;
  int tid = threadIdx.x;
  int wid = tid >> 6, lane = tid & 63;
  int g = lane >> 4, l4 = lane & 15;
  const char* h1b = (const char*)(h1 + (size_t)b*NROWS*128);

  if (tid < 32){
    int i = tile*32 + tid;
    sdeg[tid] = (i < Nk) ? cur[i] : 0;
  }
  __syncthreads();

  // stage csr tile (nontemporal), per-slot patch: slot >= deg(row) -> Nk
  {
    const u32x4* src = (const u32x4*)(csrsrc + (size_t)tile*32*CAPk);
    u32x4* dst = (u32x4*)scol;
    #pragma unroll
    for (int h=0; h<2; ++h){
      int idx = h*256 + tid;
      u32x4 v = __builtin_nontemporal_load(src + idx);
      int row = idx >> 4;            // 16 quads per row
      int p = (idx & 15) * 4;        // slot within row (multiple of 4)
      int d = min(sdeg[row], CAPk);
      if (p+0 >= d) v.x = Nk;
      if (p+1 >= d) v.y = Nk;
      if (p+2 >= d) v.z = Nk;
      if (p+3 >= d) v.w = Nk;
      dst[idx] = v;
    }
  }
  __syncthreads();

  // phase 1: 4 rows per wave, group g owns row (wid*8 + c*4 + g) entirely
  #pragma unroll
  for (int c=0;c<2;c++){
    int rg = wid*8 + c*4 + g;
    int ig = tile*32 + rg;
    int dc = sdeg[rg];
    int d4 = (min(dc, CAPk) + 3) & ~3;
    int km = d4;
    km = max(km, __shfl_xor(km, 16));
    km = max(km, __shfl_xor(km, 32));   // wave-uniform trip count

    // self row early (always valid: zero rows beyond Nk)
    u32x4 sv = *(const u32x4*)(h1b + (size_t)ig*256 + l4*16);

    f32x2 a0={0.f,0.f}, a1={0.f,0.f}, a2={0.f,0.f}, a3={0.f,0.f};
    const int* colg = scol + rg*CAPk;
    for (int k=0; k<km; k+=4){
      int4 js = *(const int4*)(colg + k);          // one ds_read_b128: 4 j's
      u32x4 v0 = *(const u32x4*)(h1b + (size_t)js.x*256 + l4*16);
      u32x4 v1 = *(const u32x4*)(h1b + (size_t)js.y*256 + l4*16);
      u32x4 v2 = *(const u32x4*)(h1b + (size_t)js.z*256 + l4*16);
      u32x4 v3 = *(const u32x4*)(h1b + (size_t)js.w*256 + l4*16);
      a0 = pk_add(a0, bf2_to_f32x2(v0.x));
      a1 = pk_add(a1, bf2_to_f32x2(v0.y));
      a2 = pk_add(a2, bf2_to_f32x2(v0.z));
      a3 = pk_add(a3, bf2_to_f32x2(v0.w));
      a0 = pk_add(a0, bf2_to_f32x2(v1.x));
      a1 = pk_add(a1, bf2_to_f32x2(v1.y));
      a2 = pk_add(a2, bf2_to_f32x2(v1.z));
      a3 = pk_add(a3, bf2_to_f32x2(v1.w));
      a0 = pk_add(a0, bf2_to_f32x2(v2.x));
      a1 = pk_add(a1, bf2_to_f32x2(v2.y));
      a2 = pk_add(a2, bf2_to_f32x2(v2.z));
      a3 = pk_add(a3, bf2_to_f32x2(v2.w));
      a0 = pk_add(a0, bf2_to_f32x2(v3.x));
      a1 = pk_add(a1, bf2_to_f32x2(v3.y));
      a2 = pk_add(a2, bf2_to_f32x2(v3.z));
      a3 = pk_add(a3, bf2_to_f32x2(v3.w));
    }
    float inv = 1.f/fmaxf((float)dc, 1.f);
    u32x4 outv;
    outv.x = pack_bf2(a0.x*inv, a0.y*inv);
    outv.y = pack_bf2(a1.x*inv, a1.y*inv);
    outv.z = pack_bf2(a2.x*inv, a2.y*inv);
    outv.w = pack_bf2(a3.x*inv, a3.y*inv);
    unsigned swz = (unsigned)((rg & 7) << 4);
    *(u32x4*)(At + rg*512 + ((unsigned)(l4*16) ^ swz))       = outv;
    *(u32x4*)(At + rg*512 + ((unsigned)(256 + l4*16) ^ swz)) = sv;
  }
  __syncthreads();

  // phase 2: GEMM 32x256 @ 256x128; wave w -> cols 32w..32w+31
  int lr = lane & 15, lk = lane >> 4;
  f32x4 acc[2][2];
  #pragma unroll
  for (int mf=0; mf<2; ++mf)
    #pragma unroll
    for (int q=0; q<2; ++q) acc[mf][q] = (f32x4){0.f,0.f,0.f,0.f};

  unsigned rsw = (unsigned)((lr & 7) << 4);
  #pragma unroll
  for (int kk=0; kk<8; ++kk){
    unsigned cb = kk*64 + lk*16;
    s16x8 a0 = *(const s16x8*)(At + lr*512      + (cb ^ rsw));
    s16x8 a1 = *(const s16x8*)(At + (16+lr)*512 + (cb ^ rsw));
    #pragma unroll
    for (int q=0; q<2; ++q){
      int nf = wid*2 + q;
      s16x8 bfr = *(const s16x8*)(const void*)(wbt + (nf*16+lr)*256 + kk*32 + lk*8);
      mfma_bf16(acc[0][q], a0, bfr);
      mfma_bf16(acc[1][q], a1, bfr);
    }
  }

  // epilogue: relu(acc + b2), mask pad rows, column-reduce, atomic into pooled
  #pragma unroll
  for (int q=0; q<2; ++q){
    int colc = (wid*2+q)*16 + lr;
    float bias = b2[colc];
    float v = 0.f;
    #pragma unroll
    for (int mf=0; mf<2; ++mf){
      int rbase = tile*32 + mf*16 + lk*4;
      #pragma unroll
      for (int r=0;r<4;++r){
        float val = fmaxf(acc[mf][q][r] + bias, 0.f);
        if (rbase + r < Nk) v += val;
      }
    }
    v += __shfl_xor(v, 16);
    v += __shfl_xor(v, 32);
    if (lane < 16) atomicAdd(&pooled[b*Hk + colc], v);
  }
}

__global__ void k7_final(const float* __restrict__ pooled, const float* __restrict__ Wro1,
                         const float* __restrict__ bro1, const float* __restrict__ Wro2,
                         const float* __restrict__ bro2, float* __restrict__ out){
  int b = blockIdx.x, t = threadIdx.x;
  __shared__ float pool[128];
  __shared__ float hid[128];
  pool[t] = pooled[b*Hk + t] * (1.0f/(float)Nk);
  __syncthreads();
  float s = bro1[t];
  for (int d=0; d<128; ++d) s += Wro1[t*128+d]*pool[d];
  hid[t] = fmaxf(s, 0.f);
  __syncthreads();
  if (t < Zk){
    float s2 = bro2[t];
    for (int d=0; d<128; ++d) s2 += Wro2[t*128+d]*hid[d];
    out[b*Zk + t] = s2;
  }
}

extern "C" void kernel_launch(void* const* d_in, const int* in_sizes, int n_in,
                              void* d_out, int out_size, void* d_ws, size_t ws_size,
                              hipStream_t stream) {
  const float* x    = (const float*)d_in[0];
  const int*   ei   = (const int*)d_in[1];
  const float* W1l  = (const float*)d_in[2];
  const float* b1   = (const float*)d_in[3];
  const float* W1r  = (const float*)d_in[4];
  const float* W2l  = (const float*)d_in[5];
  const float* b2   = (const float*)d_in[6];
  const float* W2r  = (const float*)d_in[7];
  const float* Wro1 = (const float*)d_in[8];
  const float* bro1 = (const float*)d_in[9];
  const float* Wro2 = (const float*)d_in[10];
  const float* bro2 = (const float*)d_in[11];
  float* out = (float*)d_out;

  // workspace layout (bytes, 256-aligned)
  char* ws = (char*)d_ws;
  int*   cur    = (int*)(ws + 0);              // 40000
  float* pooled = (float*)(ws + 40448);        // 4096
  __hip_bfloat16* wbt = (__hip_bfloat16*)(ws + 44544);    // 65536
  int*   csrsrc = (int*)(ws + 110080);         // 10016*64*4 = 2564096
  __hip_bfloat16* h1 = (__hip_bfloat16*)(ws + 2674176);   // 8*10016*128*2 = 20512768

  k0_init<<<dim3(128), 256, 0, stream>>>(W2l, W2r, wbt, cur, pooled);
  k3_fill<<<dim3((Ek+255)/256), 256, 0, stream>>>(ei, cur, csrsrc);
  k45_h1<<<dim3(2504), 256, 0, stream>>>(x, cur, csrsrc, W1l, b1, W1r, h1);
  kB_fused<<<dim3(Bk, NTILES), 256, 0, stream>>>(h1, cur, csrsrc, wbt, b2, pooled);
  k7_final<<<dim3(Bk), 128, 0, stream>>>(pooled, Wro1, bro1, Wro2, bro2, out);
}

// Round 12
// 87.068 us; speedup vs baseline: 1.5206x; 1.0002x over previous
//
#include <hip/hip_runtime.h>
#include <hip/hip_bf16.h>

// Problem constants
#define Bk 8
#define Nk 10000
#define Ek 160000
#define Hk 128
#define Zk 64
#define CAPk 64      // bucket-CSR capacity; deg ~ Poisson(16), P(deg>=64) ~ 0
#define NTILES 313   // ceil(10000/32)
#define NROWS 10016  // h1/csr rows per batch (incl. zero rows; rows >= Nk are zero)

typedef float f32x4 __attribute__((ext_vector_type(4)));
typedef float f32x2 __attribute__((ext_vector_type(2)));
typedef short s16x8 __attribute__((ext_vector_type(8)));
typedef unsigned u32x4 __attribute__((ext_vector_type(4)));

__device__ inline f32x2 pk_add(f32x2 a, f32x2 b){
  f32x2 d; asm("v_pk_add_f32 %0, %1, %2" : "=v"(d) : "v"(a), "v"(b)); return d;
}
__device__ inline f32x2 bf2_to_f32x2(unsigned v){
  f32x2 r; r.x = __uint_as_float(v<<16); r.y = __uint_as_float(v & 0xffff0000u); return r;
}
__device__ inline unsigned pack_bf2(float lo, float hi){
  __hip_bfloat162 p; p.x = __float2bfloat16(lo); p.y = __float2bfloat16(hi);
  return *(unsigned*)&p;
}

// init: pack WBT (128x256 bf16: [W2l | W2r] rows), zero cur + pooled
__global__ __launch_bounds__(256) void k0_init(const float* __restrict__ W2l, const float* __restrict__ W2r,
                                               __hip_bfloat16* __restrict__ wbt, int* __restrict__ cur,
                                               float* __restrict__ pooled){
  int t = blockIdx.x*256 + threadIdx.x;
  if (t < 128*256){
    int o = t >> 8, k = t & 255;
    float v = (k < 128) ? W2l[o*128+k] : W2r[o*128+(k-128)];
    wbt[t] = __float2bfloat16(v);
  }
  if (t < Nk) cur[t] = 0;
  if (t < Bk*Hk) pooled[t] = 0.f;
}

// bucket-CSR fill: csrsrc[d*CAP + p] = src, cur[d] = degree
__global__ void k3_fill(const int* __restrict__ ei, int* __restrict__ cur, int* __restrict__ csrsrc){
  int e = blockIdx.x*blockDim.x + threadIdx.x;
  if (e < Ek){
    int s = ei[e], d = ei[Ek+e];
    int p = atomicAdd(&cur[d], 1);
    if (p < CAPk) csrsrc[d*CAPk + p] = s;
  }
}

// Fused agg1 + H1: one wave per node. Lane k gathers edge k's x (exec-masked),
// 6-shfl butterfly -> agg1 in-register -> h1 row = relu(agg1*w1l + x_i*w1r + b1)
// stored bf16. Zero rows for i in [Nk, NROWS).
__global__ __launch_bounds__(256) void k45_h1(const float* __restrict__ x, const int* __restrict__ cur,
                        const int* __restrict__ csrsrc,
                        const float* __restrict__ W1l, const float* __restrict__ b1,
                        const float* __restrict__ W1r, __hip_bfloat16* __restrict__ h1){
  int i = blockIdx.x*4 + (threadIdx.x>>6);
  int lane = threadIdx.x & 63;
  if (i >= Nk){
    if (i < NROWS){
      #pragma unroll
      for (int b=0;b<Bk;b++)
        *(unsigned*)((void*)(h1 + ((size_t)b*NROWS + i)*128 + 2*lane)) = 0u;
    }
    return;
  }
  float2 wl = *(const float2*)(W1l + 2*lane);
  float2 wr = *(const float2*)(W1r + 2*lane);
  float2 bb = *(const float2*)(b1  + 2*lane);
  int degc = cur[i];
  int deg = min(degc, CAPk);
  const int* col = csrsrc + (size_t)i*CAPk;
  int j = 0;
  bool havej = (lane < deg);
  if (havej) j = col[lane];
  float inv = 1.f/fmaxf((float)degc, 1.f);

  float xx[Bk];
  #pragma unroll
  for (int b=0;b<Bk;b++){
    float v = 0.f;
    if (havej) v = x[b*Nk + j];
    xx[b] = v;
  }
  #pragma unroll
  for (int b=0;b<Bk;b++){
    float s = xx[b];
    s += __shfl_xor(s, 1);  s += __shfl_xor(s, 2);  s += __shfl_xor(s, 4);
    s += __shfl_xor(s, 8);  s += __shfl_xor(s, 16); s += __shfl_xor(s, 32);
    float a  = s * inv;
    float xi = x[b*Nk + i];
    float v0 = fmaxf(fmaf(a, wl.x, fmaf(xi, wr.x, bb.x)), 0.f);
    float v1 = fmaxf(fmaf(a, wl.y, fmaf(xi, wr.y, bb.y)), 0.f);
    *(unsigned*)((void*)(h1 + ((size_t)b*NROWS + i)*128 + 2*lane)) = pack_bf2(v0, v1);
  }
}

__device__ inline void mfma_bf16(f32x4& d, s16x8 a, s16x8 b){
  asm("v_mfma_f32_16x16x32_bf16 %0, %1, %2, %0" : "+v"(d) : "v"(a), "v"(b));
}

// Fused layer-2: csr tile in LDS (per-slot pad-patch -> zero row Nk), agg2
// gather with DUAL-ROW interleave: each 16-lane group owns rows rgA, rgB;
// one loop, two wave-uniform guards, 8 independent dwordx4 row-loads in
// flight per wave. 32-bit voffsets (slice = 2.56 MB). Then LDS A-tile
// [agg2|h1] -> MFMA -> relu+bias -> column-sum -> atomic pooled.
// batch = blockIdx.x == XCD -> per-XCD L2-resident h1.
__global__ __launch_bounds__(256) void kB_fused(const __hip_bfloat16* __restrict__ h1,
                        const int* __restrict__ cur, const int* __restrict__ csrsrc,
                        const __hip_bfloat16* __restrict__ wbt, const float* __restrict__ b2,
                        float* __restrict__ pooled){
  __shared__ char At[32*512];        // 32 rows x 256 bf16, XOR-swizzled
  __shared__ int scol[32*CAPk];      // 8 KB csr tile (pad-patched)
  __shared__ int sdeg[32];
  int b = blockIdx.x, tile = blockIdx.y;
  int tid = threadIdx.x;
  int wid = tid >> 6, lane = tid & 63;
  int g = lane >> 4, l4 = lane & 15;
  const char* h1b = (const char*)(h1 + (size_t)b*NROWS*128);
  unsigned loff = (unsigned)(l4*16);

  if (tid < 32){
    int i = tile*32 + tid;
    sdeg[tid] = (i < Nk) ? cur[i] : 0;
  }
  __syncthreads();

  // stage csr tile (nontemporal), per-slot patch: slot >= deg(row) -> Nk
  {
    const u32x4* src = (const u32x4*)(csrsrc + (size_t)tile*32*CAPk);
    u32x4* dst = (u32x4*)scol;
    #pragma unroll
    for (int h=0; h<2; ++h){
      int idx = h*256 + tid;
      u32x4 v = __builtin_nontemporal_load(src + idx);
      int row = idx >> 4;            // 16 quads per row
      int p = (idx & 15) * 4;        // slot within row (multiple of 4)
      int d = min(sdeg[row], CAPk);
      if (p+0 >= d) v.x = Nk;
      if (p+1 >= d) v.y = Nk;
      if (p+2 >= d) v.z = Nk;
      if (p+3 >= d) v.w = Nk;
      dst[idx] = v;
    }
  }
  __syncthreads();

  // phase 1: group g owns rows rgA = wid*8+g, rgB = wid*8+4+g (two streams)
  {
    int rgA = wid*8 + g,     rgB = wid*8 + 4 + g;
    int igA = tile*32 + rgA, igB = tile*32 + rgB;
    int dcA = sdeg[rgA],     dcB = sdeg[rgB];
    int kmA = (min(dcA, CAPk) + 3) & ~3;
    kmA = max(kmA, __shfl_xor(kmA, 16));
    kmA = max(kmA, __shfl_xor(kmA, 32));   // wave-uniform
    int kmB = (min(dcB, CAPk) + 3) & ~3;
    kmB = max(kmB, __shfl_xor(kmB, 16));
    kmB = max(kmB, __shfl_xor(kmB, 32));   // wave-uniform

    // self rows early (always valid: zero rows beyond Nk)
    u32x4 svA = *(const u32x4*)(h1b + (unsigned)(igA*256) + loff);
    u32x4 svB = *(const u32x4*)(h1b + (unsigned)(igB*256) + loff);

    f32x2 aA0={0.f,0.f}, aA1={0.f,0.f}, aA2={0.f,0.f}, aA3={0.f,0.f};
    f32x2 aB0={0.f,0.f}, aB1={0.f,0.f}, aB2={0.f,0.f}, aB3={0.f,0.f};
    const int* colA = scol + rgA*CAPk;
    const int* colB = scol + rgB*CAPk;
    int km = max(kmA, kmB);
    for (int k=0; k<km; k+=4){
      if (k < kmA){
        int4 js = *(const int4*)(colA + k);          // ds_read_b128: 4 j's
        u32x4 v0 = *(const u32x4*)(h1b + (unsigned)(js.x*256) + loff);
        u32x4 v1 = *(const u32x4*)(h1b + (unsigned)(js.y*256) + loff);
        u32x4 v2 = *(const u32x4*)(h1b + (unsigned)(js.z*256) + loff);
        u32x4 v3 = *(const u32x4*)(h1b + (unsigned)(js.w*256) + loff);
        aA0 = pk_add(aA0, bf2_to_f32x2(v0.x)); aA1 = pk_add(aA1, bf2_to_f32x2(v0.y));
        aA2 = pk_add(aA2, bf2_to_f32x2(v0.z)); aA3 = pk_add(aA3, bf2_to_f32x2(v0.w));
        aA0 = pk_add(aA0, bf2_to_f32x2(v1.x)); aA1 = pk_add(aA1, bf2_to_f32x2(v1.y));
        aA2 = pk_add(aA2, bf2_to_f32x2(v1.z)); aA3 = pk_add(aA3, bf2_to_f32x2(v1.w));
        aA0 = pk_add(aA0, bf2_to_f32x2(v2.x)); aA1 = pk_add(aA1, bf2_to_f32x2(v2.y));
        aA2 = pk_add(aA2, bf2_to_f32x2(v2.z)); aA3 = pk_add(aA3, bf2_to_f32x2(v2.w));
        aA0 = pk_add(aA0, bf2_to_f32x2(v3.x)); aA1 = pk_add(aA1, bf2_to_f32x2(v3.y));
        aA2 = pk_add(aA2, bf2_to_f32x2(v3.z)); aA3 = pk_add(aA3, bf2_to_f32x2(v3.w));
      }
      if (k < kmB){
        int4 js = *(const int4*)(colB + k);
        u32x4 v0 = *(const u32x4*)(h1b + (unsigned)(js.x*256) + loff);
        u32x4 v1 = *(const u32x4*)(h1b + (unsigned)(js.y*256) + loff);
        u32x4 v2 = *(const u32x4*)(h1b + (unsigned)(js.z*256) + loff);
        u32x4 v3 = *(const u32x4*)(h1b + (unsigned)(js.w*256) + loff);
        aB0 = pk_add(aB0, bf2_to_f32x2(v0.x)); aB1 = pk_add(aB1, bf2_to_f32x2(v0.y));
        aB2 = pk_add(aB2, bf2_to_f32x2(v0.z)); aB3 = pk_add(aB3, bf2_to_f32x2(v0.w));
        aB0 = pk_add(aB0, bf2_to_f32x2(v1.x)); aB1 = pk_add(aB1, bf2_to_f32x2(v1.y));
        aB2 = pk_add(aB2, bf2_to_f32x2(v1.z)); aB3 = pk_add(aB3, bf2_to_f32x2(v1.w));
        aB0 = pk_add(aB0, bf2_to_f32x2(v2.x)); aB1 = pk_add(aB1, bf2_to_f32x2(v2.y));
        aB2 = pk_add(aB2, bf2_to_f32x2(v2.z)); aB3 = pk_add(aB3, bf2_to_f32x2(v2.w));
        aB0 = pk_add(aB0, bf2_to_f32x2(v3.x)); aB1 = pk_add(aB1, bf2_to_f32x2(v3.y));
        aB2 = pk_add(aB2, bf2_to_f32x2(v3.z)); aB3 = pk_add(aB3, bf2_to_f32x2(v3.w));
      }
    }
    float invA = 1.f/fmaxf((float)dcA, 1.f);
    float invB = 1.f/fmaxf((float)dcB, 1.f);
    unsigned swzA = (unsigned)((rgA & 7) << 4);
    unsigned swzB = (unsigned)((rgB & 7) << 4);
    u32x4 oA, oB;
    oA.x = pack_bf2(aA0.x*invA, aA0.y*invA);
    oA.y = pack_bf2(aA1.x*invA, aA1.y*invA);
    oA.z = pack_bf2(aA2.x*invA, aA2.y*invA);
    oA.w = pack_bf2(aA3.x*invA, aA3.y*invA);
    oB.x = pack_bf2(aB0.x*invB, aB0.y*invB);
    oB.y = pack_bf2(aB1.x*invB, aB1.y*invB);
    oB.z = pack_bf2(aB2.x*invB, aB2.y*invB);
    oB.w = pack_bf2(aB3.x*invB, aB3.y*invB);
    *(u32x4*)(At + rgA*512 + ((unsigned)(l4*16) ^ swzA))       = oA;
    *(u32x4*)(At + rgA*512 + ((unsigned)(256 + l4*16) ^ swzA)) = svA;
    *(u32x4*)(At + rgB*512 + ((unsigned)(l4*16) ^ swzB))       = oB;
    *(u32x4*)(At + rgB*512 + ((unsigned)(256 + l4*16) ^ swzB)) = svB;
  }
  __syncthreads();

  // phase 2: GEMM 32x256 @ 256x128; wave w -> cols 32w..32w+31
  int lr = lane & 15, lk = lane >> 4;
  f32x4 acc[2][2];
  #pragma unroll
  for (int mf=0; mf<2; ++mf)
    #pragma unroll
    for (int q=0; q<2; ++q) acc[mf][q] = (f32x4){0.f,0.f,0.f,0.f};

  unsigned rsw = (unsigned)((lr & 7) << 4);
  #pragma unroll
  for (int kk=0; kk<8; ++kk){
    unsigned cb = kk*64 + lk*16;
    s16x8 a0 = *(const s16x8*)(At + lr*512      + (cb ^ rsw));
    s16x8 a1 = *(const s16x8*)(At + (16+lr)*512 + (cb ^ rsw));
    #pragma unroll
    for (int q=0; q<2; ++q){
      int nf = wid*2 + q;
      s16x8 bfr = *(const s16x8*)(const void*)(wbt + (nf*16+lr)*256 + kk*32 + lk*8);
      mfma_bf16(acc[0][q], a0, bfr);
      mfma_bf16(acc[1][q], a1, bfr);
    }
  }

  // epilogue: relu(acc + b2), mask pad rows, column-reduce, atomic into pooled
  #pragma unroll
  for (int q=0; q<2; ++q){
    int colc = (wid*2+q)*16 + lr;
    float bias = b2[colc];
    float v = 0.f;
    #pragma unroll
    for (int mf=0; mf<2; ++mf){
      int rbase = tile*32 + mf*16 + lk*4;
      #pragma unroll
      for (int r=0;r<4;++r){
        float val = fmaxf(acc[mf][q][r] + bias, 0.f);
        if (rbase + r < Nk) v += val;
      }
    }
    v += __shfl_xor(v, 16);
    v += __shfl_xor(v, 32);
    if (lane < 16) atomicAdd(&pooled[b*Hk + colc], v);
  }
}

__global__ void k7_final(const float* __restrict__ pooled, const float* __restrict__ Wro1,
                         const float* __restrict__ bro1, const float* __restrict__ Wro2,
                         const float* __restrict__ bro2, float* __restrict__ out){
  int b = blockIdx.x, t = threadIdx.x;
  __shared__ float pool[128];
  __shared__ float hid[128];
  pool[t] = pooled[b*Hk + t] * (1.0f/(float)Nk);
  __syncthreads();
  float s = bro1[t];
  for (int d=0; d<128; ++d) s += Wro1[t*128+d]*pool[d];
  hid[t] = fmaxf(s, 0.f);
  __syncthreads();
  if (t < Zk){
    float s2 = bro2[t];
    for (int d=0; d<128; ++d) s2 += Wro2[t*128+d]*hid[d];
    out[b*Zk + t] = s2;
  }
}

extern "C" void kernel_launch(void* const* d_in, const int* in_sizes, int n_in,
                              void* d_out, int out_size, void* d_ws, size_t ws_size,
                              hipStream_t stream) {
  const float* x    = (const float*)d_in[0];
  const int*   ei   = (const int*)d_in[1];
  const float* W1l  = (const float*)d_in[2];
  const float* b1   = (const float*)d_in[3];
  const float* W1r  = (const float*)d_in[4];
  const float* W2l  = (const float*)d_in[5];
  const float* b2   = (const float*)d_in[6];
  const float* W2r  = (const float*)d_in[7];
  const float* Wro1 = (const float*)d_in[8];
  const float* bro1 = (const float*)d_in[9];
  const float* Wro2 = (const float*)d_in[10];
  const float* bro2 = (const float*)d_in[11];
  float* out = (float*)d_out;

  // workspace layout (bytes, 256-aligned)
  char* ws = (char*)d_ws;
  int*   cur    = (int*)(ws + 0);              // 40000
  float* pooled = (float*)(ws + 40448);        // 4096
  __hip_bfloat16* wbt = (__hip_bfloat16*)(ws + 44544);    // 65536
  int*   csrsrc = (int*)(ws + 110080);         // 10016*64*4 = 2564096
  __hip_bfloat16* h1 = (__hip_bfloat16*)(ws + 2674176);   // 8*10016*128*2 = 20512768

  k0_init<<<dim3(128), 256, 0, stream>>>(W2l, W2r, wbt, cur, pooled);
  k3_fill<<<dim3((Ek+255)/256), 256, 0, stream>>>(ei, cur, csrsrc);
  k45_h1<<<dim3(2504), 256, 0, stream>>>(x, cur, csrsrc, W1l, b1, W1r, h1);
  kB_fused<<<dim3(Bk, NTILES), 256, 0, stream>>>(h1, cur, csrsrc, wbt, b2, pooled);
  k7_final<<<dim3(Bk), 128, 0, stream>>>(pooled, Wro1, bro1, Wro2, bro2, out);
}